// Round 10
// baseline (322.799 us; speedup 1.0000x reference)
//
#include <hip/hip_runtime.h>
#include <hip/hip_bf16.h>

#define B_ 2
#define N_ 2048
#define H_ 8
#define DH_ 128
#define D_ 1024
#define NO_ 3072
#define SCALE_ 0.08838834764831845f
#define QSCALE_ (0.08838834764831845f * 1.4426950408889634f)  // fold log2(e): base-2 softmax

typedef __bf16 bf16;
typedef __bf16 bf16x4 __attribute__((ext_vector_type(4)));
typedef __bf16 bf16x8 __attribute__((ext_vector_type(8)));
typedef float f32x4 __attribute__((ext_vector_type(4)));

__device__ inline f32x4 mfma16(bf16x8 a, bf16x8 b, f32x4 c) {
  return __builtin_amdgcn_mfma_f32_16x16x32_bf16(a, b, c, 0, 0, 0);
}

__device__ inline float elu1(float x) { return x > 0.f ? x + 1.f : __expf(x); }

// async global->LDS 16B: lds dest = wave-uniform base + lane*16
__device__ inline void gl_lds16(const bf16* g, bf16* l) {
  __builtin_amdgcn_global_load_lds(
      (const __attribute__((address_space(1))) unsigned int*)g,
      (__attribute__((address_space(3))) unsigned int*)l, 16, 0, 0);
}

// ---- setup: w_qkv->bf16, w_out->bf16, mem_kv transpose->bf16, init outputs ----
__global__ __launch_bounds__(256) void k_setup(const float* __restrict__ w_qkv,
                                               const float* __restrict__ w_out,
                                               const float* __restrict__ mem_kv,
                                               const float* __restrict__ mem_norm,
                                               bf16x4* __restrict__ wqb,
                                               bf16x4* __restrict__ wob,
                                               bf16* __restrict__ mkvT,
                                               float* __restrict__ out_kv,
                                               float* __restrict__ out_norm) {
  int id = blockIdx.x, t = threadIdx.x;
  if (id < 3072) {
    int i = id * 256 + t;
    float4 v = ((const float4*)w_qkv)[i];
    bf16x4 o; o[0]=(bf16)v.x; o[1]=(bf16)v.y; o[2]=(bf16)v.z; o[3]=(bf16)v.w;
    wqb[i] = o;
  } else if (id < 4096) {
    int i = (id - 3072) * 256 + t;
    float4 v = ((const float4*)w_out)[i];
    bf16x4 o; o[0]=(bf16)v.x; o[1]=(bf16)v.y; o[2]=(bf16)v.z; o[3]=(bf16)v.w;
    wob[i] = o;
  } else if (id < 4112) {
    int bh = id - 4096;
    int v = t & 127, khalf = t >> 7;
    const float* src = mem_kv + (size_t)bh * DH_ * DH_;
    bf16* dst = mkvT + (size_t)bh * DH_ * DH_ + (size_t)v * DH_ + khalf * 64;
#pragma unroll
    for (int kk8 = 0; kk8 < 8; kk8++) {
      int k0 = khalf * 64 + kk8 * 8;
      bf16x8 o;
#pragma unroll
      for (int e = 0; e < 8; e++) o[e] = (bf16)src[(size_t)(k0 + e) * DH_ + v];
      *(bf16x8*)(dst + kk8 * 8) = o;
    }
  } else if (id < 5136) {
    int i = (id - 4112) * 256 + t;
    out_kv[i] = mem_kv[i];
  } else {
    int i = (id - 5136) * 256 + t;
    out_norm[i] = mem_norm[i];
  }
}

// ---------------- RMSNorm: x[4096][1024] -> xn bf16 ----------------
__global__ __launch_bounds__(256) void k_rmsnorm(const float* __restrict__ x,
                                                 const float* __restrict__ gamma,
                                                 bf16* __restrict__ xn) {
  int row = blockIdx.x;
  int t = threadIdx.x;
  const float4* xr = (const float4*)(x + (size_t)row * D_);
  float4 xv = xr[t];
  float ss = xv.x*xv.x + xv.y*xv.y + xv.z*xv.z + xv.w*xv.w;
#pragma unroll
  for (int m = 1; m < 64; m <<= 1) ss += __shfl_xor(ss, m);
  __shared__ float sred[4];
  if ((t & 63) == 0) sred[t >> 6] = ss;
  __syncthreads();
  float tot = sred[0] + sred[1] + sred[2] + sred[3];
  float scale = 32.0f / fmaxf(sqrtf(tot), 1e-12f);
  float4 gv = ((const float4*)gamma)[t];
  bf16x4 ov;
  ov[0] = (bf16)(xv.x * scale * gv.x);
  ov[1] = (bf16)(xv.y * scale * gv.y);
  ov[2] = (bf16)(xv.z * scale * gv.z);
  ov[3] = (bf16)(xv.w * scale * gv.w);
  *(bf16x4*)(xn + (size_t)row * D_ + t * 4) = ov;
}

// --- C[M][N] = A[M][K] @ B[N][K]^T, m97-style global_load_lds staging ---
template <typename OT>
__global__ __launch_bounds__(256) void k_gemm_lds(const bf16* __restrict__ A,
                                                  const bf16* __restrict__ B,
                                                  OT* __restrict__ C,
                                                  int M, int Nn, int K) {
  __shared__ __align__(16) bf16 sA[128 * 32];
  __shared__ __align__(16) bf16 sB[128 * 32];
  int t = threadIdx.x;
  int w = t >> 6, lane = t & 63, quad = lane >> 4, l16 = lane & 15;
  int m0 = blockIdx.y * 128, n0 = blockIdx.x * 128;
  int wr = (w & 1) * 64, wc = (w >> 1) * 64;
  f32x4 zf = {0.f, 0.f, 0.f, 0.f};
  f32x4 acc[4][4];
#pragma unroll
  for (int a = 0; a < 4; a++)
#pragma unroll
    for (int c = 0; c < 4; c++) acc[a][c] = zf;
  int srow = w * 16 + (lane >> 2);
  int scol = (lane & 3) * 8;
  const bf16* gA = A + (size_t)(m0 + srow) * K + scol;
  const bf16* gB = B + (size_t)(n0 + srow) * K + scol;
  bf16* lA0 = sA + (size_t)w * 16 * 32;
  bf16* lA1 = sA + (size_t)(64 + w * 16) * 32;
  bf16* lB0 = sB + (size_t)w * 16 * 32;
  bf16* lB1 = sB + (size_t)(64 + w * 16) * 32;
  for (int k0 = 0; k0 < K; k0 += 32) {
    __syncthreads();
    gl_lds16(gA + k0, lA0);
    gl_lds16(gA + (size_t)64 * K + k0, lA1);
    gl_lds16(gB + k0, lB0);
    gl_lds16(gB + (size_t)64 * K + k0, lB1);
    __syncthreads();
    bf16x8 af[4], bfr[4];
#pragma unroll
    for (int mt = 0; mt < 4; mt++)
      af[mt] = *(const bf16x8*)(sA + (wr + mt * 16 + l16) * 32 + quad * 8);
#pragma unroll
    for (int nt = 0; nt < 4; nt++)
      bfr[nt] = *(const bf16x8*)(sB + (wc + nt * 16 + l16) * 32 + quad * 8);
#pragma unroll
    for (int mt = 0; mt < 4; mt++)
#pragma unroll
      for (int nt = 0; nt < 4; nt++)
        acc[mt][nt] = mfma16(af[mt], bfr[nt], acc[mt][nt]);
  }
#pragma unroll
  for (int mt = 0; mt < 4; mt++)
#pragma unroll
    for (int nt = 0; nt < 4; nt++) {
      int row = m0 + wr + mt * 16 + quad * 4;
      int col = n0 + wc + nt * 16 + l16;
      OT* cp = C + (size_t)row * Nn + col;
#pragma unroll
      for (int r = 0; r < 4; r++) cp[(size_t)r * Nn] = (OT)acc[mt][nt][r];
    }
}

// --- prep2: RoPE(q,k)->qr,kr; kf,v -> kfT,vT; qden/kden; out_norm atomics ---
// qr is pre-scaled by SCALE*log2(e) for attn2's base-2 softmax.
__global__ __launch_bounds__(256) void k_prep2(const bf16* __restrict__ qkv,
                                               const float* __restrict__ mem_norm,
                                               bf16* __restrict__ qr, bf16* __restrict__ kr,
                                               bf16* __restrict__ vT, bf16* __restrict__ kfT,
                                               float* __restrict__ qden, float* __restrict__ kden,
                                               float* __restrict__ out_norm) {
  __shared__ __align__(16) bf16 sQ[64 * 136], sK[64 * 136], sV[64 * 136];
  __shared__ float smn[128];
  int n0 = blockIdx.x * 64, h = blockIdx.y, b = blockIdx.z;
  size_t bh = (size_t)b * H_ + h;
  int t = threadIdx.x;
#pragma unroll
  for (int p = 0; p < 4; p++) {
    int i = p * 256 + t;
    int row = i >> 4, c16 = i & 15;
    size_t base = ((size_t)b * N_ + n0 + row) * NO_ + (size_t)h * DH_;
    ((uint4*)sQ)[row * 17 + c16] = *((const uint4*)(qkv + base) + c16);
    ((uint4*)sK)[row * 17 + c16] = *((const uint4*)(qkv + base + D_) + c16);
    ((uint4*)sV)[row * 17 + c16] = *((const uint4*)(qkv + base + 2 * D_) + c16);
  }
  if (t < 128) smn[t] = mem_norm[bh * DH_ + t];
  __syncthreads();
  int row = t >> 1, h2 = t & 1, d0 = h2 * 64;
  int n = n0 + row;
  float sq = 0.f, sk = 0.f;
  const float cexp = 13.287712379549449f / 128.0f;  // log2(10000)/128
#pragma unroll 2
  for (int c = 0; c < 8; c++) {
    bf16x8 q8 = *(const bf16x8*)(sQ + row * 136 + d0 + c * 8);
    bf16x8 k8 = *(const bf16x8*)(sK + row * 136 + d0 + c * 8);
    bf16x8 qo, ko, kf8;
#pragma unroll
    for (int e = 0; e < 8; e += 2) {
      int d = d0 + c * 8 + e;
      float invf = exp2f(-(float)d * cexp);
      float ang = (float)n * invf;
      float sn, cs;
      __sincosf(ang, &sn, &cs);
      float qx = (float)q8[e] * QSCALE_, qy = (float)q8[e + 1] * QSCALE_;
      qo[e]     = (bf16)(qx * cs - qy * sn);
      qo[e + 1] = (bf16)(qy * cs + qx * sn);
      float kx = (float)k8[e], ky = (float)k8[e + 1];
      ko[e]     = (bf16)(kx * cs - ky * sn);
      ko[e + 1] = (bf16)(ky * cs + kx * sn);
      float f0 = elu1(kx), f1 = elu1(ky);
      kf8[e] = (bf16)f0; kf8[e + 1] = (bf16)f1;
      sk += f0 * smn[d] + f1 * smn[d + 1];
      sq += elu1((float)q8[e]) * smn[d] + elu1((float)q8[e + 1]) * smn[d + 1];
    }
    *(bf16x8*)(qr + (bh * N_ + n) * DH_ + d0 + c * 8) = qo;
    *(bf16x8*)(kr + (bh * N_ + n) * DH_ + d0 + c * 8) = ko;
    *(bf16x8*)(sK + row * 136 + d0 + c * 8) = kf8;  // in place; region owned by this thread
  }
  sq += __shfl_xor(sq, 1);
  sk += __shfl_xor(sk, 1);
  if (h2 == 0) { qden[bh * N_ + n] = sq; kden[bh * N_ + n] = sk; }
  __syncthreads();
  // transpose out: kfT, vT rows d (128), cols n (64); accumulate new_norm partials
  int d = t >> 1, part = t & 1;
  float snorm = 0.f;
#pragma unroll
  for (int v8 = 0; v8 < 4; v8++) {
    bf16x8 okf, ov;
#pragma unroll
    for (int e = 0; e < 8; e++) {
      int nn = part * 32 + v8 * 8 + e;
      okf[e] = sK[nn * 136 + d];
      ov[e]  = sV[nn * 136 + d];
      snorm += (float)okf[e];
    }
    size_t o = (bh * DH_ + d) * N_ + n0 + part * 32 + v8 * 8;
    *(bf16x8*)(kfT + o) = okf;
    *(bf16x8*)(vT + o)  = ov;
  }
  atomicAdd(out_norm + bh * DH_ + d, snorm);
}

// ------- flash attention, K-chunked, base-2 softmax -------
#define KSTR 136
#define VSTR 72
__global__ __launch_bounds__(256) void k_attn2(const bf16* __restrict__ qr,
                                               const bf16* __restrict__ kr,
                                               const bf16* __restrict__ vT,
                                               bf16* __restrict__ attn_out,
                                               bf16* __restrict__ pO,
                                               float* __restrict__ pstat) {
  __shared__ __align__(16) bf16 sK[64 * KSTR];
  __shared__ __align__(16) bf16 sV[128 * VSTR];
  __shared__ __align__(16) bf16 sP[4][16 * VSTR];
  int x = blockIdx.x;
  size_t bh = x / 80;
  int e = x % 80;
  int qt, c;
  if (e < 32)      { qt = 31 - (e >> 2); c = e & 3; }
  else if (e < 56) { int u = e - 32; qt = 23 - u / 3; c = u % 3; }
  else if (e < 72) { int u = e - 56; qt = 15 - (u >> 1); c = u & 1; }
  else             { qt = 7 - (e - 72); c = 0; }
  int jt0 = c * 8;
  int jt1 = min(jt0 + 8, qt + 1);

  int t = threadIdx.x;
  int w = t >> 6, lane = t & 63, quad = lane >> 4, l16 = lane & 15;
  int qlo = qt * 64 + w * 16;

  bf16x8 qfrag[4];
  const bf16* qrow = qr + (bh * N_ + qlo + l16) * DH_;
#pragma unroll
  for (int s = 0; s < 4; s++) qfrag[s] = *(const bf16x8*)(qrow + s * 32 + quad * 8);

  f32x4 zf = {0.f, 0.f, 0.f, 0.f};
  f32x4 o[8];
#pragma unroll
  for (int i = 0; i < 8; i++) o[i] = zf;
  float mrow[4] = {-1e30f, -1e30f, -1e30f, -1e30f};
  float lrow[4] = {0.f, 0.f, 0.f, 0.f};

  for (int jt = jt0; jt < jt1; jt++) {
    __syncthreads();
    {
      const uint4* ksrc = (const uint4*)(kr + (bh * N_ + (size_t)jt * 64) * DH_);
#pragma unroll
      for (int p = 0; p < 4; p++) {
        int i = p * 256 + t;
        int row = i >> 4, c16 = i & 15;
        ((uint4*)sK)[row * 17 + c16] = ksrc[row * 16 + c16];
      }
#pragma unroll
      for (int p = 0; p < 4; p++) {
        int i = p * 256 + t;
        int row = i >> 3, c8 = i & 7;
        ((uint4*)sV)[row * 9 + c8] =
            *((const uint4*)(vT + (bh * DH_ + row) * N_ + (size_t)jt * 64) + c8);
      }
    }
    __syncthreads();

    f32x4 sf[4];
#pragma unroll
    for (int nt = 0; nt < 4; nt++) sf[nt] = zf;
#pragma unroll
    for (int s = 0; s < 4; s++) {
#pragma unroll
      for (int nt = 0; nt < 4; nt++) {
        bf16x8 b = *(const bf16x8*)(sK + (nt * 16 + l16) * KSTR + s * 32 + quad * 8);
        sf[nt] = mfma16(qfrag[s], b, sf[nt]);
      }
    }
    if (jt == qt) {
#pragma unroll
      for (int nt = 0; nt < 4; nt++) {
        int kg = jt * 64 + nt * 16 + l16;
#pragma unroll
        for (int r = 0; r < 4; r++) {
          int qg = qlo + quad * 4 + r;
          if (kg > qg) sf[nt][r] = -1e30f;
        }
      }
    }
    float alpha[4];
#pragma unroll
    for (int r = 0; r < 4; r++) {
      float tm = fmaxf(fmaxf(sf[0][r], sf[1][r]), fmaxf(sf[2][r], sf[3][r]));
      tm = fmaxf(tm, __shfl_xor(tm, 1));
      tm = fmaxf(tm, __shfl_xor(tm, 2));
      tm = fmaxf(tm, __shfl_xor(tm, 4));
      tm = fmaxf(tm, __shfl_xor(tm, 8));
      float mn = fmaxf(mrow[r], tm);
      alpha[r] = exp2f(mrow[r] - mn);
      float rs = 0.f;
#pragma unroll
      for (int nt = 0; nt < 4; nt++) {
        float p = exp2f(sf[nt][r] - mn);
        sf[nt][r] = p;
        rs += p;
      }
      rs += __shfl_xor(rs, 1);
      rs += __shfl_xor(rs, 2);
      rs += __shfl_xor(rs, 4);
      rs += __shfl_xor(rs, 8);
      lrow[r] = lrow[r] * alpha[r] + rs;
      mrow[r] = mn;
    }
#pragma unroll
    for (int i = 0; i < 8; i++) {
      o[i][0] *= alpha[0]; o[i][1] *= alpha[1];
      o[i][2] *= alpha[2]; o[i][3] *= alpha[3];
    }
    bf16* pw = sP[w];
#pragma unroll
    for (int nt = 0; nt < 4; nt++)
#pragma unroll
      for (int r = 0; r < 4; r++)
        pw[(quad * 4 + r) * VSTR + nt * 16 + l16] = (bf16)sf[nt][r];
    bf16x8 pa0 = *(const bf16x8*)(pw + l16 * VSTR + quad * 8);
    bf16x8 pa1 = *(const bf16x8*)(pw + l16 * VSTR + 32 + quad * 8);
#pragma unroll
    for (int vt = 0; vt < 8; vt++) {
      bf16x8 b0 = *(const bf16x8*)(sV + (vt * 16 + l16) * VSTR + quad * 8);
      bf16x8 b1 = *(const bf16x8*)(sV + (vt * 16 + l16) * VSTR + 32 + quad * 8);
      o[vt] = mfma16(pa0, b0, o[vt]);
      o[vt] = mfma16(pa1, b1, o[vt]);
    }
  }

  if (qt < 8) {
#pragma unroll
    for (int vt = 0; vt < 8; vt++)
#pragma unroll
      for (int r = 0; r < 4; r++) {
        int qg = qlo + quad * 4 + r;
        attn_out[(bh * N_ + qg) * DH_ + vt * 16 + l16] = (bf16)(o[vt][r] / lrow[r]);
      }
  } else {
    int cid = ((int)bh * 24 + qt - 8) * 4 + c;
    if (l16 == 0) {
#pragma unroll
      for (int r = 0; r < 4; r++) {
        size_t si = ((size_t)cid * 64 + w * 16 + quad * 4 + r) * 2;
        pstat[si] = mrow[r];
        pstat[si + 1] = lrow[r];
      }
    }
#pragma unroll
    for (int vt = 0; vt < 8; vt++)
#pragma unroll
      for (int r = 0; r < 4; r++) {
        int lr = w * 16 + quad * 4 + r;
        pO[((size_t)cid * 64 + lr) * DH_ + vt * 16 + l16] = (bf16)o[vt][r];
      }
  }
}

// ------- MFMA retrieval + fused flash-combine + gate + vnT -------
#define SMT_STRIDE 136
#define VNSTR 138
__global__ __launch_bounds__(256) void k_retrieve3(const bf16* __restrict__ qkv,
                                                   const bf16* __restrict__ mkvT,
                                                   const float* __restrict__ qden,
                                                   const float* __restrict__ kden,
                                                   const bf16* __restrict__ attn,
                                                   const bf16* __restrict__ pO,
                                                   const float* __restrict__ pstat,
                                                   const float* __restrict__ hg,
                                                   bf16* __restrict__ comb,
                                                   bf16* __restrict__ vnT) {
  __shared__ __align__(16) bf16 smT[DH_ * SMT_STRIDE];
  __shared__ bf16 sVn[64 * VNSTR];
  __shared__ float sW[64][4];
  int qt = blockIdx.x;
  int h = blockIdx.y, b = blockIdx.z;
  size_t bh = (size_t)b * H_ + h;
  int t = threadIdx.x;
  int w = t >> 6, lane = t & 63, quad = lane >> 4, l16 = lane & 15;
  int n0 = qt * 64;

  {
    const uint4* src = (const uint4*)(mkvT + bh * DH_ * DH_);
    uint4* dst = (uint4*)smT;
#pragma unroll
    for (int it = 0; it < 8; it++) {
      int i = t + it * 256;
      int row = i >> 4, col = i & 15;
      dst[row * 17 + col] = src[i];
    }
  }

  int nch = 0, cidb = 0;
  if (qt >= 8) {  // fused flash-decoding combine weights, per q-row
    nch = (qt + 8) / 8;
    cidb = ((int)bh * 24 + qt - 8) * 4;
    if (t < 64) {
      float ms[4], ls[4];
      float mg = -1e30f;
#pragma unroll 4
      for (int c = 0; c < nch; c++) {
        float2 st = *(const float2*)(pstat + ((size_t)(cidb + c) * 64 + t) * 2);
        ms[c] = st.x; ls[c] = st.y;
        mg = fmaxf(mg, st.x);
      }
      float L = 0.f, wcv[4];
#pragma unroll 4
      for (int c = 0; c < nch; c++) { wcv[c] = exp2f(ms[c] - mg); L += ls[c] * wcv[c]; }
      float inv = 1.f / L;
#pragma unroll 4
      for (int c = 0; c < nch; c++) sW[t][c] = wcv[c] * inv;
    }
  }

  int nrow = n0 + w * 16 + l16;
  const bf16* base = qkv + ((size_t)b * N_ + nrow) * NO_ + h * DH_;
  bf16x8 qa[4], ka[4];
#pragma unroll
  for (int s = 0; s < 4; s++) {
    int k0 = s * 32 + quad * 8;
    bf16x8 q8 = *(const bf16x8*)(base + k0);
    bf16x8 k8 = *(const bf16x8*)(base + D_ + k0);
    bf16x8 qo, ko;
#pragma unroll
    for (int e2 = 0; e2 < 8; e2++) {
      qo[e2] = (bf16)elu1((float)q8[e2]);
      ko[e2] = (bf16)elu1((float)k8[e2]);
    }
    qa[s] = qo; ka[s] = ko;
  }

  __syncthreads();
  f32x4 zf = {0.f, 0.f, 0.f, 0.f};
  f32x4 accq[8], acck[8];
#pragma unroll
  for (int vt = 0; vt < 8; vt++) { accq[vt] = zf; acck[vt] = zf; }
#pragma unroll
  for (int vt = 0; vt < 8; vt++) {
#pragma unroll
    for (int s = 0; s < 4; s++) {
      bf16x8 bfr = *(const bf16x8*)(smT + (vt * 16 + l16) * SMT_STRIDE + s * 32 + quad * 8);
      accq[vt] = mfma16(qa[s], bfr, accq[vt]);
      acck[vt] = mfma16(ka[s], bfr, acck[vt]);
    }
  }

  float g = 1.f / (1.f + __expf(-hg[h]));
#pragma unroll
  for (int r = 0; r < 4; r++) {
    int nl = w * 16 + quad * 4 + r;
    int n = n0 + nl;
    size_t m = (size_t)b * N_ + n;
    float qd = fmaxf(qden[bh * N_ + n], 1e-10f);
    float kd = fmaxf(kden[bh * N_ + n], 1e-10f);
#pragma unroll
    for (int vt = 0; vt < 8; vt++) {
      int v = vt * 16 + l16;
      float mo = accq[vt][r] / qd;
      float ov;
      if (qt < 8) {
        ov = (float)attn[(bh * N_ + n) * DH_ + v];
      } else {
        ov = 0.f;
#pragma unroll 4
        for (int c = 0; c < nch; c++)
          ov += sW[nl][c] * (float)pO[((size_t)(cidb + c) * 64 + nl) * DH_ + v];
      }
      comb[m * D_ + h * DH_ + v] = (bf16)(ov * g + mo * (1.f - g));
      float vv = (float)qkv[m * NO_ + 2 * D_ + h * DH_ + v];
      sVn[nl * VNSTR + v] = (bf16)(vv - acck[vt][r] / kd);
    }
  }
  __syncthreads();
  // transpose out vnT: rows v (128), cols n (64)
  int d = t >> 1, part = t & 1;
#pragma unroll
  for (int v8 = 0; v8 < 4; v8++) {
    bf16x8 ov;
#pragma unroll
    for (int e2 = 0; e2 < 8; e2++) ov[e2] = sVn[(part * 32 + v8 * 8 + e2) * VNSTR + d];
    *(bf16x8*)(vnT + (bh * DH_ + d) * N_ + n0 + part * 32 + v8 * 8) = ov;
  }
}

// ---- new_kv: out_kv[bh] += kfT[bh] @ vnT[bh]^T, split-K over n ----
#define GSTR 40
__global__ __launch_bounds__(256) void k_newkv2(const bf16* __restrict__ kfT,
                                                const bf16* __restrict__ vnT,
                                                float* __restrict__ out_kv) {
  __shared__ __align__(16) bf16 sA[128 * GSTR];
  __shared__ __align__(16) bf16 sB[128 * GSTR];
  int t = threadIdx.x;
  int w = t >> 6, lane = t & 63, quad = lane >> 4, l16 = lane & 15;
  size_t bh = (size_t)blockIdx.z * H_ + blockIdx.y;
  const bf16* A  = kfT + bh * DH_ * N_;
  const bf16* Bm = vnT + bh * DH_ * N_;
  int wr = (w & 1) * 64, wc = (w >> 1) * 64;
  f32x4 zf = {0.f, 0.f, 0.f, 0.f};
  f32x4 acc[4][4];
#pragma unroll
  for (int a = 0; a < 4; a++)
#pragma unroll
    for (int c = 0; c < 4; c++) acc[a][c] = zf;
  int trow = t >> 2, tc = t & 3;
  int kend = (blockIdx.x + 1) * 128;
  for (int k0 = blockIdx.x * 128; k0 < kend; k0 += 32) {
    __syncthreads();
    ((uint4*)sA)[trow * 5 + tc]        = *((const uint4*)(A + (size_t)trow * N_ + k0) + tc);
    ((uint4*)sA)[(trow + 64) * 5 + tc] = *((const uint4*)(A + (size_t)(trow + 64) * N_ + k0) + tc);
    ((uint4*)sB)[trow * 5 + tc]        = *((const uint4*)(Bm + (size_t)trow * N_ + k0) + tc);
    ((uint4*)sB)[(trow + 64) * 5 + tc] = *((const uint4*)(Bm + (size_t)(trow + 64) * N_ + k0) + tc);
    __syncthreads();
    bf16x8 af[4], bfr[4];
#pragma unroll
    for (int mt = 0; mt < 4; mt++)
      af[mt] = *(const bf16x8*)(sA + (wr + mt * 16 + l16) * GSTR + quad * 8);
#pragma unroll
    for (int nt = 0; nt < 4; nt++)
      bfr[nt] = *(const bf16x8*)(sB + (wc + nt * 16 + l16) * GSTR + quad * 8);
#pragma unroll
    for (int mt = 0; mt < 4; mt++)
#pragma unroll
      for (int nt = 0; nt < 4; nt++)
        acc[mt][nt] = mfma16(af[mt], bfr[nt], acc[mt][nt]);
  }
  float* obh = out_kv + bh * DH_ * DH_;
#pragma unroll
  for (int mt = 0; mt < 4; mt++)
#pragma unroll
    for (int nt = 0; nt < 4; nt++) {
      int row = wr + mt * 16 + quad * 4;
      int col = wc + nt * 16 + l16;
#pragma unroll
      for (int r = 0; r < 4; r++)
        atomicAdd(obh + (size_t)(row + r) * DH_ + col, acc[mt][nt][r]);
    }
}

extern "C" void kernel_launch(void* const* d_in, const int* in_sizes, int n_in,
                              void* d_out, int out_size, void* d_ws, size_t ws_size,
                              hipStream_t stream) {
  const float* x        = (const float*)d_in[0];
  const float* gamma    = (const float*)d_in[1];
  const float* w_qkv    = (const float*)d_in[2];
  const float* w_out    = (const float*)d_in[3];
  const float* hg       = (const float*)d_in[4];
  const float* mem_kv   = (const float*)d_in[5];
  const float* mem_norm = (const float*)d_in[6];
  float* out      = (float*)d_out;
  float* out_kv   = out + (size_t)B_ * N_ * D_;
  float* out_norm = out_kv + (size_t)B_ * H_ * DH_ * DH_;

  char* ws = (char*)d_ws;
  size_t off = 0;
  auto alloc = [&](size_t bytes) -> void* {
    void* p = ws + off;
    off += (bytes + 255) & ~(size_t)255;
    return p;
  };
  bf16*  xn   = (bf16*)alloc((size_t)B_ * N_ * D_ * 2);
  bf16*  wqb  = (bf16*)alloc((size_t)NO_ * D_ * 2);
  bf16*  wob  = (bf16*)alloc((size_t)D_ * D_ * 2);
  bf16*  qkvb = (bf16*)alloc((size_t)B_ * N_ * NO_ * 2);
  bf16*  qr   = (bf16*)alloc((size_t)B_ * H_ * N_ * DH_ * 2);
  bf16*  kr   = (bf16*)alloc((size_t)B_ * H_ * N_ * DH_ * 2);
  bf16*  vT   = (bf16*)alloc((size_t)B_ * H_ * DH_ * N_ * 2);
  bf16*  kfT  = (bf16*)alloc((size_t)B_ * H_ * DH_ * N_ * 2);
  float* qden = (float*)alloc((size_t)B_ * H_ * N_ * 4);
  float* kden = (float*)alloc((size_t)B_ * H_ * N_ * 4);
  bf16*  attnb= (bf16*)alloc((size_t)B_ * H_ * N_ * DH_ * 2);
  bf16*  mkvT = (bf16*)alloc((size_t)B_ * H_ * DH_ * DH_ * 2);
  bf16*  pO   = (bf16*)alloc((size_t)1536 * 64 * DH_ * 2);
  float* pstat= (float*)alloc((size_t)1536 * 64 * 2 * 4);
  // comb/vnT alias qr/kr: both dead after k_attn2; retrieve3 writes them.
  bf16*  comb = qr;
  bf16*  vnT  = kr;
  (void)in_sizes; (void)n_in; (void)out_size; (void)ws_size;

  k_setup<<<dim3(5144), 256, 0, stream>>>(w_qkv, w_out, mem_kv, mem_norm,
                                          (bf16x4*)wqb, (bf16x4*)wob, mkvT, out_kv, out_norm);
  k_rmsnorm<<<dim3(B_ * N_), 256, 0, stream>>>(x, gamma, xn);
  k_gemm_lds<bf16><<<dim3(NO_ / 128, B_ * N_ / 128), 256, 0, stream>>>(xn, wqb, qkvb, B_ * N_, NO_, D_);
  k_prep2<<<dim3(N_ / 64, H_, B_), 256, 0, stream>>>(qkvb, mem_norm, qr, kr, vT, kfT, qden, kden, out_norm);
  k_attn2<<<dim3(1280), 256, 0, stream>>>(qr, kr, vT, attnb, pO, pstat);
  k_retrieve3<<<dim3(N_ / 64, H_, B_), 256, 0, stream>>>(qkvb, mkvT, qden, kden, attnb, pO, pstat, hg, comb, vnT);
  k_gemm_lds<float><<<dim3(D_ / 128, B_ * N_ / 128), 256, 0, stream>>>(comb, wob, out, B_ * N_, D_, D_);
  k_newkv2<<<dim3(16, H_, B_), 256, 0, stream>>>(kfT, vnT, out_kv);
}

// Round 11
// 318.502 us; speedup vs baseline: 1.0135x; 1.0135x over previous
//
#include <hip/hip_runtime.h>
#include <hip/hip_bf16.h>

#define B_ 2
#define N_ 2048
#define H_ 8
#define DH_ 128
#define D_ 1024
#define NO_ 3072
#define SCALE_ 0.08838834764831845f
#define QSCALE_ (0.08838834764831845f * 1.4426950408889634f)  // fold log2(e): base-2 softmax

typedef __bf16 bf16;
typedef __bf16 bf16x4 __attribute__((ext_vector_type(4)));
typedef __bf16 bf16x8 __attribute__((ext_vector_type(8)));
typedef float f32x4 __attribute__((ext_vector_type(4)));

__device__ inline f32x4 mfma16(bf16x8 a, bf16x8 b, f32x4 c) {
  return __builtin_amdgcn_mfma_f32_16x16x32_bf16(a, b, c, 0, 0, 0);
}

__device__ inline float elu1(float x) { return x > 0.f ? x + 1.f : __expf(x); }
__device__ inline float fexp2(float x) { return __builtin_amdgcn_exp2f(x); }  // v_exp_f32

// async global->LDS 16B: lds dest = wave-uniform base + lane*16
__device__ inline void gl_lds16(const bf16* g, bf16* l) {
  __builtin_amdgcn_global_load_lds(
      (const __attribute__((address_space(1))) unsigned int*)g,
      (__attribute__((address_space(3))) unsigned int*)l, 16, 0, 0);
}

// ---- setup: w_qkv->bf16, w_out->bf16, mem_kv transpose->bf16, init outputs ----
__global__ __launch_bounds__(256) void k_setup(const float* __restrict__ w_qkv,
                                               const float* __restrict__ w_out,
                                               const float* __restrict__ mem_kv,
                                               const float* __restrict__ mem_norm,
                                               bf16x4* __restrict__ wqb,
                                               bf16x4* __restrict__ wob,
                                               bf16* __restrict__ mkvT,
                                               float* __restrict__ out_kv,
                                               float* __restrict__ out_norm) {
  int id = blockIdx.x, t = threadIdx.x;
  if (id < 3072) {
    int i = id * 256 + t;
    float4 v = ((const float4*)w_qkv)[i];
    bf16x4 o; o[0]=(bf16)v.x; o[1]=(bf16)v.y; o[2]=(bf16)v.z; o[3]=(bf16)v.w;
    wqb[i] = o;
  } else if (id < 4096) {
    int i = (id - 3072) * 256 + t;
    float4 v = ((const float4*)w_out)[i];
    bf16x4 o; o[0]=(bf16)v.x; o[1]=(bf16)v.y; o[2]=(bf16)v.z; o[3]=(bf16)v.w;
    wob[i] = o;
  } else if (id < 4112) {
    int bh = id - 4096;
    int v = t & 127, khalf = t >> 7;
    const float* src = mem_kv + (size_t)bh * DH_ * DH_;
    bf16* dst = mkvT + (size_t)bh * DH_ * DH_ + (size_t)v * DH_ + khalf * 64;
#pragma unroll
    for (int kk8 = 0; kk8 < 8; kk8++) {
      int k0 = khalf * 64 + kk8 * 8;
      bf16x8 o;
#pragma unroll
      for (int e = 0; e < 8; e++) o[e] = (bf16)src[(size_t)(k0 + e) * DH_ + v];
      *(bf16x8*)(dst + kk8 * 8) = o;
    }
  } else if (id < 5136) {
    int i = (id - 4112) * 256 + t;
    out_kv[i] = mem_kv[i];
  } else {
    int i = (id - 5136) * 256 + t;
    out_norm[i] = mem_norm[i];
  }
}

// ---------------- RMSNorm: x[4096][1024] -> xn bf16 ----------------
__global__ __launch_bounds__(256) void k_rmsnorm(const float* __restrict__ x,
                                                 const float* __restrict__ gamma,
                                                 bf16* __restrict__ xn) {
  int row = blockIdx.x;
  int t = threadIdx.x;
  const float4* xr = (const float4*)(x + (size_t)row * D_);
  float4 xv = xr[t];
  float ss = xv.x*xv.x + xv.y*xv.y + xv.z*xv.z + xv.w*xv.w;
#pragma unroll
  for (int m = 1; m < 64; m <<= 1) ss += __shfl_xor(ss, m);
  __shared__ float sred[4];
  if ((t & 63) == 0) sred[t >> 6] = ss;
  __syncthreads();
  float tot = sred[0] + sred[1] + sred[2] + sred[3];
  float scale = 32.0f / fmaxf(sqrtf(tot), 1e-12f);
  float4 gv = ((const float4*)gamma)[t];
  bf16x4 ov;
  ov[0] = (bf16)(xv.x * scale * gv.x);
  ov[1] = (bf16)(xv.y * scale * gv.y);
  ov[2] = (bf16)(xv.z * scale * gv.z);
  ov[3] = (bf16)(xv.w * scale * gv.w);
  *(bf16x4*)(xn + (size_t)row * D_ + t * 4) = ov;
}

// --- C[M][N] = A[M][K] @ B[N][K]^T, m97-style global_load_lds staging ---
template <typename OT>
__global__ __launch_bounds__(256) void k_gemm_lds(const bf16* __restrict__ A,
                                                  const bf16* __restrict__ B,
                                                  OT* __restrict__ C,
                                                  int M, int Nn, int K) {
  __shared__ __align__(16) bf16 sA[128 * 32];
  __shared__ __align__(16) bf16 sB[128 * 32];
  int t = threadIdx.x;
  int w = t >> 6, lane = t & 63, quad = lane >> 4, l16 = lane & 15;
  int m0 = blockIdx.y * 128, n0 = blockIdx.x * 128;
  int wr = (w & 1) * 64, wc = (w >> 1) * 64;
  f32x4 zf = {0.f, 0.f, 0.f, 0.f};
  f32x4 acc[4][4];
#pragma unroll
  for (int a = 0; a < 4; a++)
#pragma unroll
    for (int c = 0; c < 4; c++) acc[a][c] = zf;
  int srow = w * 16 + (lane >> 2);
  int scol = (lane & 3) * 8;
  const bf16* gA = A + (size_t)(m0 + srow) * K + scol;
  const bf16* gB = B + (size_t)(n0 + srow) * K + scol;
  bf16* lA0 = sA + (size_t)w * 16 * 32;
  bf16* lA1 = sA + (size_t)(64 + w * 16) * 32;
  bf16* lB0 = sB + (size_t)w * 16 * 32;
  bf16* lB1 = sB + (size_t)(64 + w * 16) * 32;
  for (int k0 = 0; k0 < K; k0 += 32) {
    __syncthreads();
    gl_lds16(gA + k0, lA0);
    gl_lds16(gA + (size_t)64 * K + k0, lA1);
    gl_lds16(gB + k0, lB0);
    gl_lds16(gB + (size_t)64 * K + k0, lB1);
    __syncthreads();
    bf16x8 af[4], bfr[4];
#pragma unroll
    for (int mt = 0; mt < 4; mt++)
      af[mt] = *(const bf16x8*)(sA + (wr + mt * 16 + l16) * 32 + quad * 8);
#pragma unroll
    for (int nt = 0; nt < 4; nt++)
      bfr[nt] = *(const bf16x8*)(sB + (wc + nt * 16 + l16) * 32 + quad * 8);
#pragma unroll
    for (int mt = 0; mt < 4; mt++)
#pragma unroll
      for (int nt = 0; nt < 4; nt++)
        acc[mt][nt] = mfma16(af[mt], bfr[nt], acc[mt][nt]);
  }
#pragma unroll
  for (int mt = 0; mt < 4; mt++)
#pragma unroll
    for (int nt = 0; nt < 4; nt++) {
      int row = m0 + wr + mt * 16 + quad * 4;
      int col = n0 + wc + nt * 16 + l16;
      OT* cp = C + (size_t)row * Nn + col;
#pragma unroll
      for (int r = 0; r < 4; r++) cp[(size_t)r * Nn] = (OT)acc[mt][nt][r];
    }
}

// --- prep2: RoPE(q,k)->qr,kr; kf,v -> kfT,vT; qden/kden; out_norm atomics ---
// qr is pre-scaled by SCALE*log2(e) for attn2's base-2 softmax.
__global__ __launch_bounds__(256) void k_prep2(const bf16* __restrict__ qkv,
                                               const float* __restrict__ mem_norm,
                                               bf16* __restrict__ qr, bf16* __restrict__ kr,
                                               bf16* __restrict__ vT, bf16* __restrict__ kfT,
                                               float* __restrict__ qden, float* __restrict__ kden,
                                               float* __restrict__ out_norm) {
  __shared__ __align__(16) bf16 sQ[64 * 136], sK[64 * 136], sV[64 * 136];
  __shared__ float smn[128];
  int n0 = blockIdx.x * 64, h = blockIdx.y, b = blockIdx.z;
  size_t bh = (size_t)b * H_ + h;
  int t = threadIdx.x;
#pragma unroll
  for (int p = 0; p < 4; p++) {
    int i = p * 256 + t;
    int row = i >> 4, c16 = i & 15;
    size_t base = ((size_t)b * N_ + n0 + row) * NO_ + (size_t)h * DH_;
    ((uint4*)sQ)[row * 17 + c16] = *((const uint4*)(qkv + base) + c16);
    ((uint4*)sK)[row * 17 + c16] = *((const uint4*)(qkv + base + D_) + c16);
    ((uint4*)sV)[row * 17 + c16] = *((const uint4*)(qkv + base + 2 * D_) + c16);
  }
  if (t < 128) smn[t] = mem_norm[bh * DH_ + t];
  __syncthreads();
  int row = t >> 1, h2 = t & 1, d0 = h2 * 64;
  int n = n0 + row;
  float sq = 0.f, sk = 0.f;
  const float cexp = 13.287712379549449f / 128.0f;  // log2(10000)/128
#pragma unroll 2
  for (int c = 0; c < 8; c++) {
    bf16x8 q8 = *(const bf16x8*)(sQ + row * 136 + d0 + c * 8);
    bf16x8 k8 = *(const bf16x8*)(sK + row * 136 + d0 + c * 8);
    bf16x8 qo, ko, kf8;
#pragma unroll
    for (int e = 0; e < 8; e += 2) {
      int d = d0 + c * 8 + e;
      float invf = fexp2(-(float)d * cexp);
      float ang = (float)n * invf;
      float sn, cs;
      __sincosf(ang, &sn, &cs);
      float qx = (float)q8[e] * QSCALE_, qy = (float)q8[e + 1] * QSCALE_;
      qo[e]     = (bf16)(qx * cs - qy * sn);
      qo[e + 1] = (bf16)(qy * cs + qx * sn);
      float kx = (float)k8[e], ky = (float)k8[e + 1];
      ko[e]     = (bf16)(kx * cs - ky * sn);
      ko[e + 1] = (bf16)(ky * cs + kx * sn);
      float f0 = elu1(kx), f1 = elu1(ky);
      kf8[e] = (bf16)f0; kf8[e + 1] = (bf16)f1;
      sk += f0 * smn[d] + f1 * smn[d + 1];
      sq += elu1((float)q8[e]) * smn[d] + elu1((float)q8[e + 1]) * smn[d + 1];
    }
    *(bf16x8*)(qr + (bh * N_ + n) * DH_ + d0 + c * 8) = qo;
    *(bf16x8*)(kr + (bh * N_ + n) * DH_ + d0 + c * 8) = ko;
    *(bf16x8*)(sK + row * 136 + d0 + c * 8) = kf8;  // in place; region owned by this thread
  }
  sq += __shfl_xor(sq, 1);
  sk += __shfl_xor(sk, 1);
  if (h2 == 0) { qden[bh * N_ + n] = sq; kden[bh * N_ + n] = sk; }
  __syncthreads();
  // transpose out: kfT, vT rows d (128), cols n (64); accumulate new_norm partials
  int d = t >> 1, part = t & 1;
  float snorm = 0.f;
#pragma unroll
  for (int v8 = 0; v8 < 4; v8++) {
    bf16x8 okf, ov;
#pragma unroll
    for (int e = 0; e < 8; e++) {
      int nn = part * 32 + v8 * 8 + e;
      okf[e] = sK[nn * 136 + d];
      ov[e]  = sV[nn * 136 + d];
      snorm += (float)okf[e];
    }
    size_t o = (bh * DH_ + d) * N_ + n0 + part * 32 + v8 * 8;
    *(bf16x8*)(kfT + o) = okf;
    *(bf16x8*)(vT + o)  = ov;
  }
  atomicAdd(out_norm + bh * DH_ + d, snorm);
}

// ------- flash attention, K-chunked, base-2 softmax (native v_exp_f32) -------
#define KSTR 136
#define VSTR 72
__global__ __launch_bounds__(256) void k_attn2(const bf16* __restrict__ qr,
                                               const bf16* __restrict__ kr,
                                               const bf16* __restrict__ vT,
                                               bf16* __restrict__ attn_out,
                                               bf16* __restrict__ pO,
                                               float* __restrict__ pstat) {
  __shared__ __align__(16) bf16 sK[64 * KSTR];
  __shared__ __align__(16) bf16 sV[128 * VSTR];
  __shared__ __align__(16) bf16 sP[4][16 * VSTR];
  int x = blockIdx.x;
  size_t bh = x / 80;
  int e = x % 80;
  int qt, c;
  if (e < 32)      { qt = 31 - (e >> 2); c = e & 3; }
  else if (e < 56) { int u = e - 32; qt = 23 - u / 3; c = u % 3; }
  else if (e < 72) { int u = e - 56; qt = 15 - (u >> 1); c = u & 1; }
  else             { qt = 7 - (e - 72); c = 0; }
  int jt0 = c * 8;
  int jt1 = min(jt0 + 8, qt + 1);

  int t = threadIdx.x;
  int w = t >> 6, lane = t & 63, quad = lane >> 4, l16 = lane & 15;
  int qlo = qt * 64 + w * 16;

  bf16x8 qfrag[4];
  const bf16* qrow = qr + (bh * N_ + qlo + l16) * DH_;
#pragma unroll
  for (int s = 0; s < 4; s++) qfrag[s] = *(const bf16x8*)(qrow + s * 32 + quad * 8);

  f32x4 zf = {0.f, 0.f, 0.f, 0.f};
  f32x4 o[8];
#pragma unroll
  for (int i = 0; i < 8; i++) o[i] = zf;
  float mrow[4] = {-1e30f, -1e30f, -1e30f, -1e30f};
  float lrow[4] = {0.f, 0.f, 0.f, 0.f};

  for (int jt = jt0; jt < jt1; jt++) {
    __syncthreads();
    {
      const uint4* ksrc = (const uint4*)(kr + (bh * N_ + (size_t)jt * 64) * DH_);
#pragma unroll
      for (int p = 0; p < 4; p++) {
        int i = p * 256 + t;
        int row = i >> 4, c16 = i & 15;
        ((uint4*)sK)[row * 17 + c16] = ksrc[row * 16 + c16];
      }
#pragma unroll
      for (int p = 0; p < 4; p++) {
        int i = p * 256 + t;
        int row = i >> 3, c8 = i & 7;
        ((uint4*)sV)[row * 9 + c8] =
            *((const uint4*)(vT + (bh * DH_ + row) * N_ + (size_t)jt * 64) + c8);
      }
    }
    __syncthreads();

    f32x4 sf[4];
#pragma unroll
    for (int nt = 0; nt < 4; nt++) sf[nt] = zf;
#pragma unroll
    for (int s = 0; s < 4; s++) {
#pragma unroll
      for (int nt = 0; nt < 4; nt++) {
        bf16x8 b = *(const bf16x8*)(sK + (nt * 16 + l16) * KSTR + s * 32 + quad * 8);
        sf[nt] = mfma16(qfrag[s], b, sf[nt]);
      }
    }
    if (jt == qt) {
#pragma unroll
      for (int nt = 0; nt < 4; nt++) {
        int kg = jt * 64 + nt * 16 + l16;
#pragma unroll
        for (int r = 0; r < 4; r++) {
          int qg = qlo + quad * 4 + r;
          if (kg > qg) sf[nt][r] = -1e30f;
        }
      }
    }
    float alpha[4];
#pragma unroll
    for (int r = 0; r < 4; r++) {
      float tm = fmaxf(fmaxf(sf[0][r], sf[1][r]), fmaxf(sf[2][r], sf[3][r]));
      tm = fmaxf(tm, __shfl_xor(tm, 1));
      tm = fmaxf(tm, __shfl_xor(tm, 2));
      tm = fmaxf(tm, __shfl_xor(tm, 4));
      tm = fmaxf(tm, __shfl_xor(tm, 8));
      float mn = fmaxf(mrow[r], tm);
      alpha[r] = fexp2(mrow[r] - mn);
      float rs = 0.f;
#pragma unroll
      for (int nt = 0; nt < 4; nt++) {
        float p = fexp2(sf[nt][r] - mn);
        sf[nt][r] = p;
        rs += p;
      }
      rs += __shfl_xor(rs, 1);
      rs += __shfl_xor(rs, 2);
      rs += __shfl_xor(rs, 4);
      rs += __shfl_xor(rs, 8);
      lrow[r] = lrow[r] * alpha[r] + rs;
      mrow[r] = mn;
    }
#pragma unroll
    for (int i = 0; i < 8; i++) {
      o[i][0] *= alpha[0]; o[i][1] *= alpha[1];
      o[i][2] *= alpha[2]; o[i][3] *= alpha[3];
    }
    bf16* pw = sP[w];
#pragma unroll
    for (int nt = 0; nt < 4; nt++)
#pragma unroll
      for (int r = 0; r < 4; r++)
        pw[(quad * 4 + r) * VSTR + nt * 16 + l16] = (bf16)sf[nt][r];
    bf16x8 pa0 = *(const bf16x8*)(pw + l16 * VSTR + quad * 8);
    bf16x8 pa1 = *(const bf16x8*)(pw + l16 * VSTR + 32 + quad * 8);
#pragma unroll
    for (int vt = 0; vt < 8; vt++) {
      bf16x8 b0 = *(const bf16x8*)(sV + (vt * 16 + l16) * VSTR + quad * 8);
      bf16x8 b1 = *(const bf16x8*)(sV + (vt * 16 + l16) * VSTR + 32 + quad * 8);
      o[vt] = mfma16(pa0, b0, o[vt]);
      o[vt] = mfma16(pa1, b1, o[vt]);
    }
  }

  if (qt < 8) {
#pragma unroll
    for (int vt = 0; vt < 8; vt++)
#pragma unroll
      for (int r = 0; r < 4; r++) {
        int qg = qlo + quad * 4 + r;
        attn_out[(bh * N_ + qg) * DH_ + vt * 16 + l16] = (bf16)(o[vt][r] / lrow[r]);
      }
  } else {
    int cid = ((int)bh * 24 + qt - 8) * 4 + c;
    if (l16 == 0) {
#pragma unroll
      for (int r = 0; r < 4; r++) {
        size_t si = ((size_t)cid * 64 + w * 16 + quad * 4 + r) * 2;
        pstat[si] = mrow[r];
        pstat[si + 1] = lrow[r];
      }
    }
#pragma unroll
    for (int vt = 0; vt < 8; vt++)
#pragma unroll
      for (int r = 0; r < 4; r++) {
        int lr = w * 16 + quad * 4 + r;
        pO[((size_t)cid * 64 + lr) * DH_ + vt * 16 + l16] = (bf16)o[vt][r];
      }
  }
}

// ------- MFMA retrieval + fused flash-combine + gate + vnT -------
#define SMT_STRIDE 136
#define VNSTR 138
__global__ __launch_bounds__(256) void k_retrieve3(const bf16* __restrict__ qkv,
                                                   const bf16* __restrict__ mkvT,
                                                   const float* __restrict__ qden,
                                                   const float* __restrict__ kden,
                                                   const bf16* __restrict__ attn,
                                                   const bf16* __restrict__ pO,
                                                   const float* __restrict__ pstat,
                                                   const float* __restrict__ hg,
                                                   bf16* __restrict__ comb,
                                                   bf16* __restrict__ vnT) {
  __shared__ __align__(16) bf16 smT[DH_ * SMT_STRIDE];
  __shared__ bf16 sVn[64 * VNSTR];
  __shared__ float sW[64][4];
  int qt = blockIdx.x;
  int h = blockIdx.y, b = blockIdx.z;
  size_t bh = (size_t)b * H_ + h;
  int t = threadIdx.x;
  int w = t >> 6, lane = t & 63, quad = lane >> 4, l16 = lane & 15;
  int n0 = qt * 64;

  {
    const uint4* src = (const uint4*)(mkvT + bh * DH_ * DH_);
    uint4* dst = (uint4*)smT;
#pragma unroll
    for (int it = 0; it < 8; it++) {
      int i = t + it * 256;
      int row = i >> 4, col = i & 15;
      dst[row * 17 + col] = src[i];
    }
  }

  int nch = 0, cidb = 0;
  if (qt >= 8) {  // fused flash-decoding combine weights, per q-row
    nch = (qt + 8) / 8;
    cidb = ((int)bh * 24 + qt - 8) * 4;
    if (t < 64) {
      float ms[4], ls[4];
      float mg = -1e30f;
#pragma unroll 4
      for (int c = 0; c < nch; c++) {
        float2 st = *(const float2*)(pstat + ((size_t)(cidb + c) * 64 + t) * 2);
        ms[c] = st.x; ls[c] = st.y;
        mg = fmaxf(mg, st.x);
      }
      float L = 0.f, wcv[4];
#pragma unroll 4
      for (int c = 0; c < nch; c++) { wcv[c] = fexp2(ms[c] - mg); L += ls[c] * wcv[c]; }
      float inv = 1.f / L;
#pragma unroll 4
      for (int c = 0; c < nch; c++) sW[t][c] = wcv[c] * inv;
    }
  }

  int nrow = n0 + w * 16 + l16;
  const bf16* base = qkv + ((size_t)b * N_ + nrow) * NO_ + h * DH_;
  bf16x8 qa[4], ka[4];
#pragma unroll
  for (int s = 0; s < 4; s++) {
    int k0 = s * 32 + quad * 8;
    bf16x8 q8 = *(const bf16x8*)(base + k0);
    bf16x8 k8 = *(const bf16x8*)(base + D_ + k0);
    bf16x8 qo, ko;
#pragma unroll
    for (int e2 = 0; e2 < 8; e2++) {
      qo[e2] = (bf16)elu1((float)q8[e2]);
      ko[e2] = (bf16)elu1((float)k8[e2]);
    }
    qa[s] = qo; ka[s] = ko;
  }

  __syncthreads();
  f32x4 zf = {0.f, 0.f, 0.f, 0.f};
  f32x4 accq[8], acck[8];
#pragma unroll
  for (int vt = 0; vt < 8; vt++) { accq[vt] = zf; acck[vt] = zf; }
#pragma unroll
  for (int vt = 0; vt < 8; vt++) {
#pragma unroll
    for (int s = 0; s < 4; s++) {
      bf16x8 bfr = *(const bf16x8*)(smT + (vt * 16 + l16) * SMT_STRIDE + s * 32 + quad * 8);
      accq[vt] = mfma16(qa[s], bfr, accq[vt]);
      acck[vt] = mfma16(ka[s], bfr, acck[vt]);
    }
  }

  float g = 1.f / (1.f + __expf(-hg[h]));
#pragma unroll
  for (int r = 0; r < 4; r++) {
    int nl = w * 16 + quad * 4 + r;
    int n = n0 + nl;
    size_t m = (size_t)b * N_ + n;
    float qd = fmaxf(qden[bh * N_ + n], 1e-10f);
    float kd = fmaxf(kden[bh * N_ + n], 1e-10f);
#pragma unroll
    for (int vt = 0; vt < 8; vt++) {
      int v = vt * 16 + l16;
      float mo = accq[vt][r] / qd;
      float ov;
      if (qt < 8) {
        ov = (float)attn[(bh * N_ + n) * DH_ + v];
      } else {
        ov = 0.f;
#pragma unroll 4
        for (int c = 0; c < nch; c++)
          ov += sW[nl][c] * (float)pO[((size_t)(cidb + c) * 64 + nl) * DH_ + v];
      }
      comb[m * D_ + h * DH_ + v] = (bf16)(ov * g + mo * (1.f - g));
      float vv = (float)qkv[m * NO_ + 2 * D_ + h * DH_ + v];
      sVn[nl * VNSTR + v] = (bf16)(vv - acck[vt][r] / kd);
    }
  }
  __syncthreads();
  // transpose out vnT: rows v (128), cols n (64)
  int d = t >> 1, part = t & 1;
#pragma unroll
  for (int v8 = 0; v8 < 4; v8++) {
    bf16x8 ov;
#pragma unroll
    for (int e2 = 0; e2 < 8; e2++) ov[e2] = sVn[(part * 32 + v8 * 8 + e2) * VNSTR + d];
    *(bf16x8*)(vnT + (bh * DH_ + d) * N_ + n0 + part * 32 + v8 * 8) = ov;
  }
}

// ---- new_kv: out_kv[bh] += kfT[bh] @ vnT[bh]^T, split-K over n ----
#define GSTR 40
__global__ __launch_bounds__(256) void k_newkv2(const bf16* __restrict__ kfT,
                                                const bf16* __restrict__ vnT,
                                                float* __restrict__ out_kv) {
  __shared__ __align__(16) bf16 sA[128 * GSTR];
  __shared__ __align__(16) bf16 sB[128 * GSTR];
  int t = threadIdx.x;
  int w = t >> 6, lane = t & 63, quad = lane >> 4, l16 = lane & 15;
  size_t bh = (size_t)blockIdx.z * H_ + blockIdx.y;
  const bf16* A  = kfT + bh * DH_ * N_;
  const bf16* Bm = vnT + bh * DH_ * N_;
  int wr = (w & 1) * 64, wc = (w >> 1) * 64;
  f32x4 zf = {0.f, 0.f, 0.f, 0.f};
  f32x4 acc[4][4];
#pragma unroll
  for (int a = 0; a < 4; a++)
#pragma unroll
    for (int c = 0; c < 4; c++) acc[a][c] = zf;
  int trow = t >> 2, tc = t & 3;
  int kend = (blockIdx.x + 1) * 128;
  for (int k0 = blockIdx.x * 128; k0 < kend; k0 += 32) {
    __syncthreads();
    ((uint4*)sA)[trow * 5 + tc]        = *((const uint4*)(A + (size_t)trow * N_ + k0) + tc);
    ((uint4*)sA)[(trow + 64) * 5 + tc] = *((const uint4*)(A + (size_t)(trow + 64) * N_ + k0) + tc);
    ((uint4*)sB)[trow * 5 + tc]        = *((const uint4*)(Bm + (size_t)trow * N_ + k0) + tc);
    ((uint4*)sB)[(trow + 64) * 5 + tc] = *((const uint4*)(Bm + (size_t)(trow + 64) * N_ + k0) + tc);
    __syncthreads();
    bf16x8 af[4], bfr[4];
#pragma unroll
    for (int mt = 0; mt < 4; mt++)
      af[mt] = *(const bf16x8*)(sA + (wr + mt * 16 + l16) * GSTR + quad * 8);
#pragma unroll
    for (int nt = 0; nt < 4; nt++)
      bfr[nt] = *(const bf16x8*)(sB + (wc + nt * 16 + l16) * GSTR + quad * 8);
#pragma unroll
    for (int mt = 0; mt < 4; mt++)
#pragma unroll
      for (int nt = 0; nt < 4; nt++)
        acc[mt][nt] = mfma16(af[mt], bfr[nt], acc[mt][nt]);
  }
  float* obh = out_kv + bh * DH_ * DH_;
#pragma unroll
  for (int mt = 0; mt < 4; mt++)
#pragma unroll
    for (int nt = 0; nt < 4; nt++) {
      int row = wr + mt * 16 + quad * 4;
      int col = wc + nt * 16 + l16;
#pragma unroll
      for (int r = 0; r < 4; r++)
        atomicAdd(obh + (size_t)(row + r) * DH_ + col, acc[mt][nt][r]);
    }
}

extern "C" void kernel_launch(void* const* d_in, const int* in_sizes, int n_in,
                              void* d_out, int out_size, void* d_ws, size_t ws_size,
                              hipStream_t stream) {
  const float* x        = (const float*)d_in[0];
  const float* gamma    = (const float*)d_in[1];
  const float* w_qkv    = (const float*)d_in[2];
  const float* w_out    = (const float*)d_in[3];
  const float* hg       = (const float*)d_in[4];
  const float* mem_kv   = (const float*)d_in[5];
  const float* mem_norm = (const float*)d_in[6];
  float* out      = (float*)d_out;
  float* out_kv   = out + (size_t)B_ * N_ * D_;
  float* out_norm = out_kv + (size_t)B_ * H_ * DH_ * DH_;

  char* ws = (char*)d_ws;
  size_t off = 0;
  auto alloc = [&](size_t bytes) -> void* {
    void* p = ws + off;
    off += (bytes + 255) & ~(size_t)255;
    return p;
  };
  bf16*  xn   = (bf16*)alloc((size_t)B_ * N_ * D_ * 2);
  bf16*  wqb  = (bf16*)alloc((size_t)NO_ * D_ * 2);
  bf16*  wob  = (bf16*)alloc((size_t)D_ * D_ * 2);
  bf16*  qkvb = (bf16*)alloc((size_t)B_ * N_ * NO_ * 2);
  bf16*  qr   = (bf16*)alloc((size_t)B_ * H_ * N_ * DH_ * 2);
  bf16*  kr   = (bf16*)alloc((size_t)B_ * H_ * N_ * DH_ * 2);
  bf16*  vT   = (bf16*)alloc((size_t)B_ * H_ * DH_ * N_ * 2);
  bf16*  kfT  = (bf16*)alloc((size_t)B_ * H_ * DH_ * N_ * 2);
  float* qden = (float*)alloc((size_t)B_ * H_ * N_ * 4);
  float* kden = (float*)alloc((size_t)B_ * H_ * N_ * 4);
  bf16*  attnb= (bf16*)alloc((size_t)B_ * H_ * N_ * DH_ * 2);
  bf16*  mkvT = (bf16*)alloc((size_t)B_ * H_ * DH_ * DH_ * 2);
  bf16*  pO   = (bf16*)alloc((size_t)1536 * 64 * DH_ * 2);
  float* pstat= (float*)alloc((size_t)1536 * 64 * 2 * 4);
  // comb/vnT alias qr/kr: both dead after k_attn2; retrieve3 writes them.
  bf16*  comb = qr;
  bf16*  vnT  = kr;
  (void)in_sizes; (void)n_in; (void)out_size; (void)ws_size;

  k_setup<<<dim3(5144), 256, 0, stream>>>(w_qkv, w_out, mem_kv, mem_norm,
                                          (bf16x4*)wqb, (bf16x4*)wob, mkvT, out_kv, out_norm);
  k_rmsnorm<<<dim3(B_ * N_), 256, 0, stream>>>(x, gamma, xn);
  k_gemm_lds<bf16><<<dim3(NO_ / 128, B_ * N_ / 128), 256, 0, stream>>>(xn, wqb, qkvb, B_ * N_, NO_, D_);
  k_prep2<<<dim3(N_ / 64, H_, B_), 256, 0, stream>>>(qkvb, mem_norm, qr, kr, vT, kfT, qden, kden, out_norm);
  k_attn2<<<dim3(1280), 256, 0, stream>>>(qr, kr, vT, attnb, pO, pstat);
  k_retrieve3<<<dim3(N_ / 64, H_, B_), 256, 0, stream>>>(qkvb, mkvT, qden, kden, attnb, pO, pstat, hg, comb, vnT);
  k_gemm_lds<float><<<dim3(D_ / 128, B_ * N_ / 128), 256, 0, stream>>>(comb, wob, out, B_ * N_, D_, D_);
  k_newkv2<<<dim3(16, H_, B_), 256, 0, stream>>>(kfT, vnT, out_kv);
}